// Round 5
// baseline (217.494 us; speedup 1.0000x reference)
//
#include <hip/hip_runtime.h>
#include <hip/hip_bf16.h>
#include <math.h>

typedef __bf16 bf16_t;
typedef __bf16 bf16x8 __attribute__((ext_vector_type(8)));
typedef float f32x4 __attribute__((ext_vector_type(4)));
typedef float f32x16 __attribute__((ext_vector_type(16)));
typedef unsigned u32x2 __attribute__((ext_vector_type(2)));

#define NPOS 4096
#define LOG2E 1.4426950408889634f

__device__ __forceinline__ f32x4 mfma16(bf16x8 a, bf16x8 b, f32x4 c) {
    return __builtin_amdgcn_mfma_f32_16x16x32_bf16(a, b, c, 0, 0, 0);
}
__device__ __forceinline__ f32x16 mfma32(bf16x8 a, bf16x8 b, f32x16 c) {
    return __builtin_amdgcn_mfma_f32_32x32x16_bf16(a, b, c, 0, 0, 0);
}

// Raw barrier: drain LDS ops only; vm loads (next-tile reg prefetch) stay in flight.
__device__ __forceinline__ void BAR() {
    asm volatile("s_waitcnt lgkmcnt(0)" ::: "memory");
    __builtin_amdgcn_sched_barrier(0);
    __builtin_amdgcn_s_barrier();
    __builtin_amdgcn_sched_barrier(0);
}

// ---- LDS tile layout (proven 0-conflict in r4): 256B rows, byte ^= (row&15)<<4 ----
template<int D>
__device__ __forceinline__ bf16x8 ldK(const char* lds, int key, int dbyte) {
    if constexpr (D == 128) {
        return *(const bf16x8*)(lds + key * 256 + (dbyte ^ ((key & 15) << 4)));
    } else {
        int row = key >> 1;
        int col = ((key & 1) << 7) | dbyte;
        return *(const bf16x8*)(lds + row * 256 + (col ^ ((row & 15) << 4)));
    }
}
__device__ __forceinline__ bf16x8 ldV(const char* lds, int d, int kbyte) {
    int row = d >> 1;
    int col = ((d & 1) << 7) | kbyte;
    return *(const bf16x8*)(lds + row * 256 + (col ^ ((row & 15) << 4)));
}

__device__ __forceinline__ unsigned pkbf(float a, float b) {
    union { bf16_t h[2]; unsigned u; } t;
    t.h[0] = (bf16_t)a; t.h[1] = (bf16_t)b;
    return t.u;
}

#define MKPA(sb, base) ({                                                   \
    unsigned a0_ = pkbf((sb)[(base)+0], (sb)[(base)+1]);                    \
    unsigned a1_ = pkbf((sb)[(base)+2], (sb)[(base)+3]);                    \
    unsigned a2_ = pkbf((sb)[(base)+4], (sb)[(base)+5]);                    \
    unsigned a3_ = pkbf((sb)[(base)+6], (sb)[(base)+7]);                    \
    u32x2 r0_ = __builtin_amdgcn_permlane32_swap(a2_, a0_, false, false);   \
    u32x2 r1_ = __builtin_amdgcn_permlane32_swap(a3_, a1_, false, false);   \
    union { unsigned u[4]; bf16x8 v; } pu_;                                 \
    pu_.u[0] = r0_.y; pu_.u[1] = r1_.y; pu_.u[2] = r0_.x; pu_.u[3] = r1_.x; \
    pu_.v; })

// ---------------- transpose + fp32->bf16 convert ----------------
__global__ __launch_bounds__(256) void k_transpose(const float* __restrict__ s2d,
                                                   const float* __restrict__ s3d,
                                                   bf16_t* __restrict__ d2d,
                                                   bf16_t* __restrict__ d3d)
{
    __shared__ float tile[64][65];
    int bid = blockIdx.x, tid = threadIdx.x;
    const float* src; bf16_t* dst; int C, b, c0, n0;
    if (bid < 1024) { src = s2d; dst = d2d; C = 256; b = bid >> 8; c0 = ((bid >> 6) & 3) << 6; n0 = (bid & 63) << 6; }
    else { int r = bid - 1024; src = s3d; dst = d3d; C = 128; b = r >> 7; c0 = ((r >> 6) & 1) << 6; n0 = (r & 63) << 6; }
    const float* sp = src + ((size_t)b * C + c0) * NPOS + n0;
#pragma unroll
    for (int i = 0; i < 16; i++) {
        int idx = tid + i * 256; int c = idx >> 6, n = idx & 63;
        tile[c][n] = sp[(size_t)c * NPOS + n];
    }
    __syncthreads();
    bf16_t* dp = dst + ((size_t)b * NPOS + n0) * C + c0;
#pragma unroll
    for (int i = 0; i < 16; i++) {
        int idx = tid + i * 256; int n = idx >> 6, c = idx & 63;
        dp[(size_t)n * C + c] = (bf16_t)tile[c][n];
    }
}

// ---------------- weight fp32->bf16 ----------------
__global__ __launch_bounds__(256) void k_weights(const float* w0, const float* w1, const float* w2, const float* w3,
                                                 const float* w4, const float* w5, const float* w6, const float* w7,
                                                 bf16_t* dst)
{
    int i = blockIdx.x * 256 + threadIdx.x;
    if      (i <  32768) dst[i] = (bf16_t)w0[i];
    else if (i <  49152) dst[i] = (bf16_t)w1[i - 32768];
    else if (i <  65536) dst[i] = (bf16_t)w2[i - 49152];
    else if (i <  98304) dst[i] = (bf16_t)w3[i - 65536];
    else if (i < 106496) dst[i] = (bf16_t)w4[i - 98304];
    else if (i < 122880) dst[i] = (bf16_t)w5[i - 106496];
    else if (i < 139264) dst[i] = (bf16_t)w6[i - 122880];
    else if (i < 147456) dst[i] = (bf16_t)w7[i - 139264];
}

// ---------------- projection GEMM ----------------
// MODE 0: out[B][N][M] bf16 = (Xt@W^T + b)*scale
// MODE 1: out[B][M][N] bf16 = W@Xt^T + b
// MODE 2: out[B][M][N] f32  = W@Xt^T + b + resid
// MODE 3: MODE 2 with X = softmax-merged A-partials (Xt=OtH base, mlp=m/l pairs)
template<int K, int M, int MODE>
__global__ __launch_bounds__(256, 2) void k_proj(const bf16_t* __restrict__ Xt,
                                                 const bf16_t* __restrict__ W,
                                                 const float* __restrict__ bias,
                                                 float scale,
                                                 const float* __restrict__ resid,
                                                 void* __restrict__ outp,
                                                 const float2* __restrict__ mlp)
{
    extern __shared__ char smem[];
    constexpr int RB = K * 2;
    int bid = blockIdx.x, tid = threadIdx.x;
    int b = bid >> 6, n0 = (bid & 63) << 6;
    int wave = tid >> 6, lane = tid & 63, g = lane >> 4, lr = lane & 15;

    if constexpr (MODE == 3) {
        // merged staging: X[n] = c1*O1n[n] + c2*O2n[n]  (K==128, RB==256)
        const bf16_t* O1 = Xt;
        const bf16_t* O2 = Xt + 2097152;
#pragma unroll
        for (int j0 = 0; j0 < 64 * RB; j0 += 4096) {
            int j = j0 + tid * 16;
            int row = j >> 8;
            int colb = j & 255;
            size_t n = (size_t)b * NPOS + n0 + row;
            float2 a1 = mlp[n], a2 = mlp[16384 + n];
            float ms = fmaxf(a1.x, a2.x);
            float w1 = exp2f(a1.x - ms) * a1.y;
            float w2 = exp2f(a2.x - ms) * a2.y;
            float inv = 1.f / (w1 + w2);
            w1 *= inv; w2 *= inv;
            bf16x8 o1 = *(const bf16x8*)(O1 + n * 128 + (colb >> 1));
            bf16x8 o2 = *(const bf16x8*)(O2 + n * 128 + (colb >> 1));
            bf16x8 xv;
#pragma unroll
            for (int e = 0; e < 8; ++e) xv[e] = (bf16_t)(w1 * (float)o1[e] + w2 * (float)o2[e]);
            *(bf16x8*)(smem + row * 256 + (colb ^ ((row & 7) << 4))) = xv;
        }
    } else {
        const char* src = (const char*)(Xt + ((size_t)b * NPOS + n0) * K);
#pragma unroll
        for (int j0 = 0; j0 < 64 * RB; j0 += 4096) {
            int j = j0 + tid * 16;
            int row = j / RB;
            int col = j & (RB - 1);
            float4 v = *(const float4*)(src + (size_t)row * RB + col);
            *(float4*)(smem + row * RB + (col ^ ((row & 7) << 4))) = v;
        }
    }
    __syncthreads();

    f32x4 acc[M / 16];
#pragma unroll
    for (int ob = 0; ob < M / 16; ++ob) acc[ob] = f32x4{0.f, 0.f, 0.f, 0.f};
    int xrow = wave * 16 + lr;
#pragma unroll
    for (int ks = 0; ks < K / 32; ++ks) {
        bf16x8 xf = *(const bf16x8*)(smem + xrow * RB + ((((ks * 32 + g * 8) * 2)) ^ ((xrow & 7) << 4)));
#pragma unroll
        for (int ob = 0; ob < M / 16; ++ob) {
            bf16x8 wf = *(const bf16x8*)(W + (size_t)(ob * 16 + lr) * K + ks * 32 + g * 8);
            if constexpr (MODE == 0) acc[ob] = mfma16(xf, wf, acc[ob]);
            else                     acc[ob] = mfma16(wf, xf, acc[ob]);
        }
    }
    if constexpr (MODE == 0) {
        bf16_t* out = (bf16_t*)outp;
#pragma unroll
        for (int ob = 0; ob < M / 16; ++ob) {
            int o = ob * 16 + lr;
            float bs = bias[o];
#pragma unroll
            for (int r = 0; r < 4; r++) {
                size_t n = (size_t)b * NPOS + n0 + wave * 16 + g * 4 + r;
                out[n * M + o] = (bf16_t)((acc[ob][r] + bs) * scale);
            }
        }
    } else {
#pragma unroll
        for (int ob = 0; ob < M / 16; ++ob) {
#pragma unroll
            for (int r = 0; r < 4; r++) {
                int o = ob * 16 + g * 4 + r;
                size_t idx = ((size_t)b * M + o) * NPOS + n0 + wave * 16 + lr;
                float v = acc[ob][r] + bias[o];
                if constexpr (MODE == 1) ((bf16_t*)outp)[idx] = (bf16_t)v;
                else                     ((float*)outp)[idx] = v + resid[idx];
            }
        }
    }
}

// ---------------- attention: stream A KV-half block (4 waves, 128q, 32 iters) ----------------
// Writes normalized partial O + (m,l) per half; merged in k_proj MODE 3.
__device__ void attnA(const bf16_t* __restrict__ Qt, const bf16_t* __restrict__ Kt,
                      const bf16_t* __restrict__ V, bf16_t* __restrict__ OtH,
                      float2* __restrict__ mlH, int b, int qtile, int half,
                      char* smem, int tid)
{
    char* Kb0 = smem;          char* Kb1 = smem + 16384;
    char* Vb0 = smem + 32768;  char* Vb1 = smem + 49152;
    int w = tid >> 6, lane = tid & 63;
    int qcol = lane & 31, hi = lane >> 5;
    int q0 = qtile * 128 + w * 32;
    int t0 = half * 32;

    bf16x8 qf[8];
    const bf16_t* qp = Qt + ((size_t)b * NPOS + q0 + qcol) * 128 + hi * 8;
#pragma unroll
    for (int ks = 0; ks < 8; ++ks) qf[ks] = *(const bf16x8*)(qp + ks * 16);

    f32x16 acc[4];
#pragma unroll
    for (int cb = 0; cb < 4; ++cb)
#pragma unroll
        for (int i = 0; i < 16; ++i) acc[cb][i] = 0.f;
    float m_c = -1e30f, l_c = 0.f;

    const char* kg = (const char*)(Kt + (size_t)b * NPOS * 128);
    const char* vg = (const char*)(V + (size_t)b * 128 * NPOS);

    int srow = w * 16 + (lane >> 4);
    int scolb = (lane & 15) * 16;
    float4 kr[4], vr[4];

    auto LD = [&](int t) {
#pragma unroll
        for (int c = 0; c < 4; ++c) {
            int r = srow + c * 4;
            kr[c] = *(const float4*)(kg + (size_t)t * 16384 + r * 256 + scolb);
            int d = (r << 1) | (scolb >> 7);
            vr[c] = *(const float4*)(vg + (size_t)d * 8192 + (size_t)t * 128 + (scolb & 127));
        }
    };
    auto WR = [&](char* Kb, char* Vb) {
#pragma unroll
        for (int c = 0; c < 4; ++c) {
            int r = srow + c * 4;
            int sw = scolb ^ ((r & 15) << 4);
            *(float4*)(Kb + r * 256 + sw) = kr[c];
            *(float4*)(Vb + r * 256 + sw) = vr[c];
        }
    };

    LD(t0);
    WR(Kb0, Vb0);
    LD(t0 + 1);
    BAR();

    for (int tl = 0; tl < 32; ++tl) {
        char* Kc = (tl & 1) ? Kb1 : Kb0;
        char* Vc = (tl & 1) ? Vb1 : Vb0;

        f32x16 s0, s1;
#pragma unroll
        for (int i = 0; i < 16; ++i) { s0[i] = 0.f; s1[i] = 0.f; }
        __builtin_amdgcn_s_setprio(1);
#pragma unroll
        for (int ks = 0; ks < 8; ++ks) {
            int dbyte = ks * 32 + hi * 16;
            bf16x8 k0 = ldK<128>(Kc, qcol, dbyte);
            bf16x8 k1 = ldK<128>(Kc, 32 + qcol, dbyte);
            s0 = mfma32(k0, qf[ks], s0);
            s1 = mfma32(k1, qf[ks], s1);
        }
        __builtin_amdgcn_s_setprio(0);

        float pmax = s0[0];
#pragma unroll
        for (int i = 1; i < 16; ++i) pmax = fmaxf(pmax, s0[i]);
#pragma unroll
        for (int i = 0; i < 16; ++i) pmax = fmaxf(pmax, s1[i]);
        pmax = fmaxf(pmax, __shfl_xor(pmax, 32));

        if (__any(pmax > m_c + 11.54156f)) {
            float mn = fmaxf(m_c, pmax);
            float fc = exp2f(m_c - mn);
            m_c = mn; l_c *= fc;
#pragma unroll
            for (int r = 0; r < 16; ++r) {
                float fr = __shfl(fc, (r & 3) + 8 * (r >> 2) + 4 * hi);
#pragma unroll
                for (int cb = 0; cb < 4; ++cb) acc[cb][r] *= fr;
            }
        }

        float psum = 0.f;
#pragma unroll
        for (int i = 0; i < 16; ++i) { s0[i] = exp2f(s0[i] - m_c); psum += s0[i]; }
#pragma unroll
        for (int i = 0; i < 16; ++i) { s1[i] = exp2f(s1[i] - m_c); psum += s1[i]; }
        psum += __shfl_xor(psum, 32);
        l_c += psum;

        bf16x8 pa0 = MKPA(s0, 0);
        bf16x8 pa1 = MKPA(s0, 8);
        bf16x8 pa2 = MKPA(s1, 0);
        bf16x8 pa3 = MKPA(s1, 8);

        __builtin_amdgcn_s_setprio(1);
#pragma unroll
        for (int cb = 0; cb < 4; ++cb) {
            int d = cb * 32 + qcol;
            acc[cb] = mfma32(pa0, ldV(Vc, d, 0  + hi * 16), acc[cb]);
            acc[cb] = mfma32(pa1, ldV(Vc, d, 32 + hi * 16), acc[cb]);
            acc[cb] = mfma32(pa2, ldV(Vc, d, 64 + hi * 16), acc[cb]);
            acc[cb] = mfma32(pa3, ldV(Vc, d, 96 + hi * 16), acc[cb]);
        }
        __builtin_amdgcn_s_setprio(0);

        if (tl < 31) {
            WR((tl & 1) ? Kb0 : Kb1, (tl & 1) ? Vb0 : Vb1);   // write t+1
            if (tl < 30) LD(t0 + tl + 2);                      // prefetch t+2
            BAR();
        }
    }

    float linv = 1.f / l_c;
    size_t obase = (size_t)(half * 4 + b) * NPOS;
#pragma unroll
    for (int r = 0; r < 16; ++r) {
        int crow = (r & 3) + 8 * (r >> 2) + 4 * hi;
        float lr = __shfl(linv, crow);
        size_t nrow = obase + q0 + crow;
#pragma unroll
        for (int cb = 0; cb < 4; ++cb)
            OtH[nrow * 128 + cb * 32 + qcol] = (bf16_t)(acc[cb][r] * lr);
    }
    if (lane < 32) mlH[obase + q0 + lane] = make_float2(m_c, l_c);
}

// ---------------- attention: stream B block (64q, full KV; 2 compute + 2 stager waves) ----------------
__device__ void attnB(const bf16_t* __restrict__ Qt, const bf16_t* __restrict__ Kt,
                      const bf16_t* __restrict__ V, bf16_t* __restrict__ Ot,
                      int b, int sub, char* smem, int tid)
{
    char* Kb0 = smem;          char* Kb1 = smem + 8192;
    char* Vb0 = smem + 16384;  char* Vb1 = smem + 24576;
    int w = tid >> 6, lane = tid & 63;
    const char* kg = (const char*)(Kt + (size_t)b * NPOS * 64);
    const char* vg = (const char*)(V + (size_t)b * 64 * NPOS);

    if (w >= 2) {
        // stager waves
        int srow = (w - 2) * 16 + (lane >> 4);
        int scolb = (lane & 15) * 16;
        float4 kr[4], vr[4];
        auto LD = [&](int t) {
#pragma unroll
            for (int c = 0; c < 4; ++c) {
                int r = srow + c * 4;
                int k = (r << 1) | (scolb >> 7);
                kr[c] = *(const float4*)(kg + (size_t)t * 8192 + (size_t)k * 128 + (scolb & 127));
                vr[c] = *(const float4*)(vg + (size_t)(k) * 8192 + (size_t)t * 128 + (scolb & 127));
            }
        };
        auto WR = [&](char* Kb, char* Vb) {
#pragma unroll
            for (int c = 0; c < 4; ++c) {
                int r = srow + c * 4;
                int sw = scolb ^ ((r & 15) << 4);
                *(float4*)(Kb + r * 256 + sw) = kr[c];
                *(float4*)(Vb + r * 256 + sw) = vr[c];
            }
        };
        LD(0);
        WR(Kb0, Vb0);
        LD(1);
        BAR();
        for (int tl = 0; tl < 63; ++tl) {
            WR((tl & 1) ? Kb0 : Kb1, (tl & 1) ? Vb0 : Vb1);
            if (tl < 62) LD(tl + 2);
            BAR();
        }
        return;
    }

    // compute waves (w = 0,1)
    int qcol = lane & 31, hi = lane >> 5;
    int q0 = sub * 64 + w * 32;
    bf16x8 qf[4];
    const bf16_t* qp = Qt + ((size_t)b * NPOS + q0 + qcol) * 64 + hi * 8;
#pragma unroll
    for (int ks = 0; ks < 4; ++ks) qf[ks] = *(const bf16x8*)(qp + ks * 16);

    f32x16 acc[2];
#pragma unroll
    for (int cb = 0; cb < 2; ++cb)
#pragma unroll
        for (int i = 0; i < 16; ++i) acc[cb][i] = 0.f;
    float m_c = -1e30f, l_c = 0.f;

    BAR();
    for (int tl = 0; tl < 64; ++tl) {
        char* Kc = (tl & 1) ? Kb1 : Kb0;
        char* Vc = (tl & 1) ? Vb1 : Vb0;

        f32x16 s0, s1;
#pragma unroll
        for (int i = 0; i < 16; ++i) { s0[i] = 0.f; s1[i] = 0.f; }
        __builtin_amdgcn_s_setprio(1);
#pragma unroll
        for (int ks = 0; ks < 4; ++ks) {
            int dbyte = ks * 32 + hi * 16;
            bf16x8 k0 = ldK<64>(Kc, qcol, dbyte);
            bf16x8 k1 = ldK<64>(Kc, 32 + qcol, dbyte);
            s0 = mfma32(k0, qf[ks], s0);
            s1 = mfma32(k1, qf[ks], s1);
        }
        __builtin_amdgcn_s_setprio(0);

        float pmax = s0[0];
#pragma unroll
        for (int i = 1; i < 16; ++i) pmax = fmaxf(pmax, s0[i]);
#pragma unroll
        for (int i = 0; i < 16; ++i) pmax = fmaxf(pmax, s1[i]);
        pmax = fmaxf(pmax, __shfl_xor(pmax, 32));

        if (__any(pmax > m_c + 11.54156f)) {
            float mn = fmaxf(m_c, pmax);
            float fc = exp2f(m_c - mn);
            m_c = mn; l_c *= fc;
#pragma unroll
            for (int r = 0; r < 16; ++r) {
                float fr = __shfl(fc, (r & 3) + 8 * (r >> 2) + 4 * hi);
#pragma unroll
                for (int cb = 0; cb < 2; ++cb) acc[cb][r] *= fr;
            }
        }

        float psum = 0.f;
#pragma unroll
        for (int i = 0; i < 16; ++i) { s0[i] = exp2f(s0[i] - m_c); psum += s0[i]; }
#pragma unroll
        for (int i = 0; i < 16; ++i) { s1[i] = exp2f(s1[i] - m_c); psum += s1[i]; }
        psum += __shfl_xor(psum, 32);
        l_c += psum;

        bf16x8 pa0 = MKPA(s0, 0);
        bf16x8 pa1 = MKPA(s0, 8);
        bf16x8 pa2 = MKPA(s1, 0);
        bf16x8 pa3 = MKPA(s1, 8);

        __builtin_amdgcn_s_setprio(1);
#pragma unroll
        for (int cb = 0; cb < 2; ++cb) {
            int d = cb * 32 + qcol;
            acc[cb] = mfma32(pa0, ldV(Vc, d, 0  + hi * 16), acc[cb]);
            acc[cb] = mfma32(pa1, ldV(Vc, d, 32 + hi * 16), acc[cb]);
            acc[cb] = mfma32(pa2, ldV(Vc, d, 64 + hi * 16), acc[cb]);
            acc[cb] = mfma32(pa3, ldV(Vc, d, 96 + hi * 16), acc[cb]);
        }
        __builtin_amdgcn_s_setprio(0);
        if (tl < 63) BAR();
    }

    float linv = 1.f / l_c;
#pragma unroll
    for (int r = 0; r < 16; ++r) {
        int crow = (r & 3) + 8 * (r >> 2) + 4 * hi;
        float lr = __shfl(linv, crow);
        size_t nrow = (size_t)b * NPOS + q0 + crow;
#pragma unroll
        for (int cb = 0; cb < 2; ++cb)
            Ot[nrow * 64 + cb * 32 + qcol] = (bf16_t)(acc[cb][r] * lr);
    }
}

__global__ __launch_bounds__(256, 2) void k_attn5(const bf16_t* QtA, const bf16_t* KtA, const bf16_t* VA,
                                                  bf16_t* OtH, float2* mlH,
                                                  const bf16_t* QtB, const bf16_t* KtB, const bf16_t* VB,
                                                  bf16_t* OtB)
{
    extern __shared__ char smem[];
    int bid = blockIdx.x, tid = threadIdx.x;
    if (bid < 256) {
        // XCD x (=bid&7) gets A-batch x>>1; blocks = (batch, qtile, half)
        int x = bid & 7;
        int u = (bid & 1) + ((bid >> 3) << 1);    // 0..63
        attnA(QtA, KtA, VA, OtH, mlH, x >> 1, u >> 1, u & 1, smem, tid);
    } else {
        int r = bid - 256;
        int x = r & 7;
        int sub = (r & 1) + ((r >> 3) << 1);      // 0..63
        attnB(QtB, KtB, VB, OtB, x >> 1, sub, smem, tid);
    }
}

extern "C" void kernel_launch(void* const* d_in, const int* in_sizes, int n_in,
                              void* d_out, int out_size, void* d_ws, size_t ws_size,
                              hipStream_t stream)
{
    (void)in_sizes; (void)n_in; (void)out_size; (void)ws_size;
    const float* f2d = (const float*)d_in[0];
    const float* f3d = (const float*)d_in[1];
    const float* wqA = (const float*)d_in[2];  const float* bqA = (const float*)d_in[3];
    const float* wkA = (const float*)d_in[4];  const float* bkA = (const float*)d_in[5];
    const float* wvA = (const float*)d_in[6];  const float* bvA = (const float*)d_in[7];
    const float* wpA = (const float*)d_in[8];  const float* bpA = (const float*)d_in[9];
    const float* wqB = (const float*)d_in[10]; const float* bqB = (const float*)d_in[11];
    const float* wkB = (const float*)d_in[12]; const float* bkB = (const float*)d_in[13];
    const float* wvB = (const float*)d_in[14]; const float* bvB = (const float*)d_in[15];
    const float* wpB = (const float*)d_in[16]; const float* bpB = (const float*)d_in[17];

    char* ws = (char*)d_ws;
    bf16_t* ft2d = (bf16_t*)(ws);                // [B][N][256]  8388608 B  (dead after producers)
    bf16_t* ft3d = (bf16_t*)(ws + 8388608);      // [B][N][128]  4194304 B  (dead after producers)
    bf16_t* wbf  = (bf16_t*)(ws + 12582912);     // 147456 elems
    bf16_t* QtA  = (bf16_t*)(ws + 12877824);     // [B][N][128]
    bf16_t* KtA_ = (bf16_t*)(ws + 17072128);
    bf16_t* VA_  = (bf16_t*)(ws + 21266432);     // [B][128][N]
    bf16_t* QtB  = (bf16_t*)(ws + 25460736);     // [B][N][64]
    bf16_t* KtB_ = (bf16_t*)(ws + 27557888);
    bf16_t* VB_  = (bf16_t*)(ws + 29655040);     // [B][64][N]
    bf16_t* OtB  = (bf16_t*)(ws + 35946496);     // [B][N][64]
    // A partials overlay the dead ft2d/ft3d region:
    bf16_t* OtH  = (bf16_t*)(ws);                // [2][B][N][128] bf16 = 8388608 B
    float2* mlH  = (float2*)(ws + 8388608);      // [2][B][N] float2 = 262144 B

    k_transpose<<<1536, 256, 0, stream>>>(f2d, f3d, ft2d, ft3d);
    k_weights<<<576, 256, 0, stream>>>(wqA, wkA, wvA, wpA, wqB, wkB, wvB, wpB, wbf);

    const float sA = 0.08838834764831845f * LOG2E;  // 128^-0.5 * log2e
    const float sB = 0.125f * LOG2E;                // 64^-0.5  * log2e

    k_proj<256, 128, 0><<<256, 256, 32768, stream>>>(ft2d, wbf +      0, bqA, sA,  nullptr, QtA, nullptr);
    k_proj<128, 128, 0><<<256, 256, 16384, stream>>>(ft3d, wbf +  32768, bkA, 1.f, nullptr, KtA_, nullptr);
    k_proj<128, 128, 1><<<256, 256, 16384, stream>>>(ft3d, wbf +  49152, bvA, 1.f, nullptr, VA_, nullptr);
    k_proj<128,  64, 0><<<256, 256, 16384, stream>>>(ft3d, wbf +  98304, bqB, sB,  nullptr, QtB, nullptr);
    k_proj<256,  64, 0><<<256, 256, 32768, stream>>>(ft2d, wbf + 106496, bkB, 1.f, nullptr, KtB_, nullptr);
    k_proj<256,  64, 1><<<256, 256, 32768, stream>>>(ft2d, wbf + 122880, bvB, 1.f, nullptr, VB_, nullptr);

    k_attn5<<<512, 256, 65536, stream>>>(QtA, KtA_, VA_, OtH, mlH, QtB, KtB_, VB_, OtB);

    k_proj<128, 256, 3><<<256, 256, 16384, stream>>>(OtH, wbf +  65536, bpA, 1.f, f2d, (float*)d_out, mlH);
    k_proj< 64, 128, 2><<<256, 256,  8192, stream>>>(OtB, wbf + 139264, bpB, 1.f, f3d, (float*)d_out + 4194304, nullptr);
}